// Round 3
// baseline (258.139 us; speedup 1.0000x reference)
//
#include <hip/hip_runtime.h>

typedef float v2f __attribute__((ext_vector_type(2)));

// Problem shape (fixed by setup_inputs)
constexpr int Bn = 256;
constexpr int Tn = 10;
constexpr int Fn = 16384;
constexpr int FQ = Fn / 4;   // float4 strips per row = 4096 (power of 2)

__device__ __forceinline__ float pk_fmaf(float a, float b, float c) { return fmaf(a, b, c); }

// Fully fused: 3x LIF-box scan over T + 1x1 conv channel-sum + time-linear.
// One thread owns 4 consecutive f's (two packed float2 pairs) for one b.
// Packed v_pk_*_f32 ops round identically to scalar -> bit-exact vs round-0.
__global__ __launch_bounds__(256) void lif_net_kernel(
    const float* __restrict__ x,
    const float* __restrict__ p_tau1, const float* __restrict__ p_tau2,
    const float* __restrict__ p_tau3,
    const float* __restrict__ p_vth1, const float* __restrict__ p_vth2,
    const float* __restrict__ p_vth3,
    const float* __restrict__ conv_w, const float* __restrict__ conv_b,
    const float* __restrict__ lin_w,  const float* __restrict__ lin_b,
    float* __restrict__ out)
{
#pragma clang fp contract(off)
    // Uniform scalar params (s_loads; L2-resident)
    const float k1 = __fmul_rn(0.001f, p_tau1[0]);   // DT * tau_inv, single-rounded
    const float k2 = __fmul_rn(0.001f, p_tau2[0]);
    const float k3 = __fmul_rn(0.001f, p_tau3[0]);
    const float th1 = p_vth1[0], th2 = p_vth2[0], th3 = p_vth3[0];
    const float w0 = conv_w[0], w1 = conv_w[1], w2 = conv_w[2];
    const float cb = conv_b[0];
    const float lb0 = lin_b[0], lb1 = lin_b[1];

    const v2f kv1 = {k1, k1}, kv2 = {k2, k2}, kv3 = {k3, k3};
    const v2f cbv = {cb, cb};

    const int idx = blockIdx.x * blockDim.x + threadIdx.x;  // 0 .. Bn*FQ-1
    const int b   = idx >> 12;        // idx / FQ
    const int fq  = idx & (FQ - 1);   // idx % FQ

    const float4* xp = reinterpret_cast<const float4*>(x + (size_t)b * Tn * Fn);

    v2f v1[2] = {{0.f, 0.f}, {0.f, 0.f}};
    v2f v2[2] = {{0.f, 0.f}, {0.f, 0.f}};
    v2f v3[2] = {{0.f, 0.f}, {0.f, 0.f}};
    v2f a0[2] = {{0.f, 0.f}, {0.f, 0.f}};
    v2f a1[2] = {{0.f, 0.f}, {0.f, 0.f}};

#pragma unroll
    for (int t = 0; t < Tn; ++t) {
        const float4 xv = xp[fq + t * FQ];
        const float lw0 = lin_w[t];        // lin_w[0][t]
        const float lw1 = lin_w[Tn + t];   // lin_w[1][t]
        v2f xpair[2];
        xpair[0] = v2f{xv.x, xv.y};
        xpair[1] = v2f{xv.z, xv.w};
#pragma unroll
        for (int p = 0; p < 2; ++p) {
            const v2f xx = xpair[p];

            // v_dec = v + k*(x - v); contract(off) keeps mul/add separate,
            // packed ops have identical per-lane IEEE rounding.
            const v2f d1  = xx - v1[p];          // v_pk_add (neg)
            const v2f m1  = kv1 * d1;            // v_pk_mul
            const v2f vd1 = v1[p] + m1;          // v_pk_add
            const v2f d2  = xx - v2[p];
            const v2f m2  = kv2 * d2;
            const v2f vd2 = v2[p] + m2;
            const v2f d3  = xx - v3[p];
            const v2f m3  = kv3 * d3;
            const v2f vd3 = v3[p] + m3;

            // (vd - th > 0) <=> (vd > th) exactly in IEEE RN
            const bool z1a = vd1.x > th1, z1b = vd1.y > th1;
            const bool z2a = vd2.x > th2, z2b = vd2.y > th2;
            const bool z3a = vd3.x > th3, z3b = vd3.y > th3;

            v1[p].x = z1a ? 0.f : vd1.x;  v1[p].y = z1b ? 0.f : vd1.y;
            v2[p].x = z2a ? 0.f : vd2.x;  v2[p].y = z2b ? 0.f : vd2.y;
            v3[p].x = z3a ? 0.f : vd3.x;  v3[p].y = z3b ? 0.f : vd3.y;

            // y = ((w0*z1 + w1*z2) + w2*z3) + cb, z in {0,1} -> exact selects
            v2f s0, s1, s2;
            s0.x = z1a ? w0 : 0.f;  s0.y = z1b ? w0 : 0.f;
            s1.x = z2a ? w1 : 0.f;  s1.y = z2b ? w1 : 0.f;
            s2.x = z3a ? w2 : 0.f;  s2.y = z3b ? w2 : 0.f;
            const v2f y = ((s0 + s1) + s2) + cbv;   // 3x v_pk_add, same order as ref

            // time-linear accumulation (smooth; fma as in round-0)
            a0[p].x = pk_fmaf(y.x, lw0, a0[p].x);
            a0[p].y = pk_fmaf(y.y, lw0, a0[p].y);
            a1[p].x = pk_fmaf(y.x, lw1, a1[p].x);
            a1[p].y = pk_fmaf(y.y, lw1, a1[p].y);
        }
    }

    float* ob = out + (size_t)b * 2 * Fn;
    float4 o0, o1;
    o0.x = __fadd_rn(a0[0].x, lb0); o0.y = __fadd_rn(a0[0].y, lb0);
    o0.z = __fadd_rn(a0[1].x, lb0); o0.w = __fadd_rn(a0[1].y, lb0);
    o1.x = __fadd_rn(a1[0].x, lb1); o1.y = __fadd_rn(a1[0].y, lb1);
    o1.z = __fadd_rn(a1[1].x, lb1); o1.w = __fadd_rn(a1[1].y, lb1);
    reinterpret_cast<float4*>(ob)[fq]      = o0;   // [b, 0, f]
    reinterpret_cast<float4*>(ob + Fn)[fq] = o1;   // [b, 1, f]
}

extern "C" void kernel_launch(void* const* d_in, const int* in_sizes, int n_in,
                              void* d_out, int out_size, void* d_ws, size_t ws_size,
                              hipStream_t stream) {
    const float* x      = (const float*)d_in[0];
    const float* tau1   = (const float*)d_in[1];
    const float* tau2   = (const float*)d_in[2];
    const float* tau3   = (const float*)d_in[3];
    const float* vth1   = (const float*)d_in[4];
    const float* vth2   = (const float*)d_in[5];
    const float* vth3   = (const float*)d_in[6];
    const float* conv_w = (const float*)d_in[7];
    const float* conv_b = (const float*)d_in[8];
    const float* lin_w  = (const float*)d_in[9];
    const float* lin_b  = (const float*)d_in[10];
    float* out = (float*)d_out;

    const int total  = Bn * FQ;          // 1,048,576 threads
    const int block  = 256;
    const int grid   = total / block;    // 4096 blocks

    lif_net_kernel<<<grid, block, 0, stream>>>(
        x, tau1, tau2, tau3, vth1, vth2, vth3, conv_w, conv_b, lin_w, lin_b, out);
}